// Round 1
// baseline (1201.082 us; speedup 1.0000x reference)
//
#include <hip/hip_runtime.h>

#define XM 30
#define YM 30
#define CELLS (XM * YM)   // 900
#define NT 1024
#define NW (NT / 64)      // 16 waves
#define NITERS 1500
#define PITERS 30

// Block-wide sum reduction. All threads must call; returns total to all.
__device__ __forceinline__ float block_reduce_sum(float v, float* red, float* scal) {
#pragma unroll
    for (int off = 32; off > 0; off >>= 1)
        v += __shfl_down(v, off, 64);
    const int lane = threadIdx.x & 63;
    const int wid = threadIdx.x >> 6;
    if (lane == 0) red[wid] = v;
    __syncthreads();
    if (threadIdx.x == 0) {
        float t = 0.f;
#pragma unroll
        for (int w = 0; w < NW; ++w) t += red[w];
        scal[0] = t;
    }
    __syncthreads();
    return scal[0];
}

__global__ __launch_bounds__(NT, 1) void pdhg_grid_lp(const float* __restrict__ weights,
                                                      float* __restrict__ out) {
    // ypub: published y_in per cell (node (i,j,'in')); also reused as u_in in power iter.
    // xpub: published xbar per out-edge by direction slot; also holds v_out in power iter.
    // Stride 9 (coprime with 32 banks) to avoid 16-way conflicts of stride 8.
    __shared__ float ypub[CELLS];
    __shared__ float xpub[CELLS][9];
    __shared__ float red[NW];
    __shared__ float scal[1];

    const int t = threadIdx.x;
    const bool act = (t < CELLS);
    const int i = t / YM;
    const int j = t % YM;

    // Direction order; opp(d) == 7-d under this enumeration.
    const int DP[8] = {-1, -1, -1, 0, 0, 1, 1, 1};
    const int DQ[8] = {-1, 0, 1, -1, 1, -1, 0, 1};

    int nbr[8];
    float validf[8];
#pragma unroll
    for (int d = 0; d < 8; ++d) {
        const int ii = i + DP[d], jj = j + DQ[d];
        const bool ok = act && (ii >= 0) && (ii < XM) && (jj >= 0) && (jj < YM);
        validf[d] = ok ? 1.f : 0.f;
        nbr[d] = ok ? (ii * YM + jj) : 0;
    }
    const float c_int = act ? weights[t] : 0.f;

    // ---------------- power iteration for L = ||A||_2 ----------------
    // v0 = ones/sqrt(V), V = 7744 = 88^2
    const float v0 = 1.0f / 88.0f;
    float v_int = act ? v0 : 0.f;
    float v_out[8];
#pragma unroll
    for (int d = 0; d < 8; ++d) v_out[d] = validf[d] * v0;
    if (act) {
#pragma unroll
        for (int d = 0; d < 8; ++d) xpub[t][d] = v_out[d];
    }
    __syncthreads();

    float L = 1.f;
    for (int it = 0; it <= PITERS; ++it) {
        // u = A v  (per node): u_in = v_int - sum(in-edges), u_out = sum(out-edges) - v_int
        float gin = 0.f;
#pragma unroll
        for (int d = 0; d < 8; ++d)
            gin += validf[d] * xpub[nbr[d]][7 - d];
        const float u_in = v_int - gin;
        float so = 0.f;
#pragma unroll
        for (int d = 0; d < 8; ++d) so += v_out[d];
        const float u_out = so - v_int;

        if (it == PITERS) {
            float p = act ? (u_in * u_in + u_out * u_out) : 0.f;
            L = sqrtf(block_reduce_sum(p, red, scal));
            break;
        }

        if (act) ypub[t] = u_in;
        __syncthreads();

        // w = A^T u  (per edge): w = u[tail] - u[head]
        const float w_int = u_in - u_out;
        float w_out[8];
        float p = act ? (w_int * w_int) : 0.f;
#pragma unroll
        for (int d = 0; d < 8; ++d) {
            const float w = validf[d] * (u_out - ypub[nbr[d]]);
            w_out[d] = w;
            p += w * w;
        }
        const float nrm = sqrtf(block_reduce_sum(p, red, scal));
        v_int = w_int / nrm;
#pragma unroll
        for (int d = 0; d < 8; ++d) v_out[d] = w_out[d] / nrm;
        if (act) {
#pragma unroll
            for (int d = 0; d < 8; ++d) xpub[t][d] = v_out[d];
        }
        __syncthreads();
    }

    const float tau = 0.95f / L;
    const float sigma = tau;

    // ---------------- PDHG main loop ----------------
    float x_int = 0.f, y_in = 0.f, y_out = 0.f;
    float x_out[8];
#pragma unroll
    for (int d = 0; d < 8; ++d) x_out[d] = 0.f;

    if (act) ypub[t] = 0.f;
    __syncthreads();

    for (int it = 0; it < NITERS; ++it) {
        // ---- phase A: x update (reads neighbor y_in from ypub) ----
        // internal edge: A^T y = y_in - y_out ; cost c_int
        const float g = c_int + (y_in - y_out);
        const float xn = fminf(fmaxf(x_int - tau * g, 0.f), 1.f);
        const float xb_int = 2.f * xn - x_int;
        x_int = xn;

        float xb_out[8];
#pragma unroll
        for (int d = 0; d < 8; ++d) {
            const float aty = y_out - ypub[nbr[d]];  // tail y_out, head = neighbor in-node
            const float xo = x_out[d];
            float xno = fminf(fmaxf(xo - tau * aty, 0.f), 1.f);
            xno *= validf[d];  // invalid dirs pinned at 0
            const float xb = 2.f * xno - xo;
            x_out[d] = xno;
            xb_out[d] = xb;
            if (act) xpub[t][d] = xb;
        }
        __syncthreads();

        // ---- phase B: y update (reads neighbor xbar from xpub) ----
        float gi = 0.f;
#pragma unroll
        for (int d = 0; d < 8; ++d)
            gi += validf[d] * xpub[nbr[d]][7 - d];
        float axb_in = xb_int - gi;  // +tail(internal) - sum(in-edges)
        float soxb = 0.f;
#pragma unroll
        for (int d = 0; d < 8; ++d) soxb += xb_out[d];
        float axb_out = soxb - xb_int;  // +sum(out-edges) - head(internal)

        // subtract b: b[node0]=+1 (cell0 'in'), b[last]=-1 (cell899 'out')
        if (t == 0) axb_in -= 1.f;
        if (t == CELLS - 1) axb_out += 1.f;

        y_in += sigma * axb_in;
        y_out += sigma * axb_out;
        if (act) ypub[t] = y_in;
        __syncthreads();
    }

    if (act) out[t] = x_int;
}

extern "C" void kernel_launch(void* const* d_in, const int* in_sizes, int n_in,
                              void* d_out, int out_size, void* d_ws, size_t ws_size,
                              hipStream_t stream) {
    const float* weights = (const float*)d_in[0];  // (30,30) f32
    // d_in[1] (dense A) and d_in[2] (b) are not needed: the incidence structure
    // is fixed and rebuilt from index math; the algorithm is equivariant under
    // edge relabeling (v0 constant, x0=y0=0).
    float* out = (float*)d_out;  // 900 f32
    (void)in_sizes; (void)n_in; (void)out_size; (void)d_ws; (void)ws_size;

    hipLaunchKernelGGL(pdhg_grid_lp, dim3(1), dim3(NT), 0, stream, weights, out);
}

// Round 2
// 745.979 us; speedup vs baseline: 1.6101x; 1.6101x over previous
//
#include <hip/hip_runtime.h>

#define XM 30
#define YM 30
#define CELLS (XM * YM)   // 900
#define NT 960
#define NW (NT / 64)      // 15 waves
#define NITERS 1500
#define PITERS 30

// Block-wide sum reduction. All threads must call; returns total to all.
__device__ __forceinline__ float block_reduce_sum(float v, float* red, float* scal) {
#pragma unroll
    for (int off = 32; off > 0; off >>= 1)
        v += __shfl_down(v, off, 64);
    const int lane = threadIdx.x & 63;
    const int wid = threadIdx.x >> 6;
    if (lane == 0) red[wid] = v;
    __syncthreads();
    if (threadIdx.x == 0) {
        float s = 0.f;
#pragma unroll
        for (int w = 0; w < NW; ++w) s += red[w];
        scal[0] = s;
    }
    __syncthreads();
    return scal[0];
}

// Edge ownership: cell t owns, for each negative direction d in {0..3}:
//   E_out(t,d) = edge (t,out) -> (nbr(t,d),in)
//   E_in (t,d) = edge (nbr(t,d),out) -> (t,in)
// Every 8-neighbor edge is owned exactly once (opp(d) = 7-d).
// ypub[t] = (y_in, y_out); xpub[s][t] = (xbar of E_out(t,s), xbar of E_in(t,s)).
// Index CELLS is a dummy cell that stays all-zero (absorbs invalid-neighbor reads).
__global__ __launch_bounds__(NT, 1) void pdhg_grid_lp(const float* __restrict__ weights,
                                                      float* __restrict__ out) {
    __shared__ float2 ypub[CELLS + 1];
    __shared__ float2 xpub[4][CELLS + 1];
    __shared__ float red[NW];
    __shared__ float scal[1];

    const int t = threadIdx.x;
    const bool act = (t < CELLS);
    const int i = t / YM;
    const int j = t % YM;

    // Direction order; opp(d) == 7-d.
    const int DP[8] = {-1, -1, -1, 0, 0, 1, 1, 1};
    const int DQ[8] = {-1, 0, 1, -1, 1, -1, 0, 1};

    int nbr[8];
    float validf[8];
#pragma unroll
    for (int d = 0; d < 8; ++d) {
        const int ii = i + DP[d], jj = j + DQ[d];
        const bool ok = act && (ii >= 0) && (ii < XM) && (jj >= 0) && (jj < YM);
        validf[d] = ok ? 1.f : 0.f;
        nbr[d] = ok ? (ii * YM + jj) : CELLS;  // invalid -> dummy zero cell
    }
    const float c_int = act ? weights[t] : 0.f;

    // init dummy cell (never written again)
    if (t == 0) {
        ypub[CELLS] = make_float2(0.f, 0.f);
#pragma unroll
        for (int s = 0; s < 4; ++s) xpub[s][CELLS] = make_float2(0.f, 0.f);
    }

    // ---------------- power iteration for L = ||A||_2 ----------------
    // v0 = ones/sqrt(V), V = 7744 = 88^2. Same math as reference, relabeled.
    const float v0 = 1.0f / 88.0f;
    float v_int = act ? v0 : 0.f;
    float vo[4], vi[4];
#pragma unroll
    for (int d = 0; d < 4; ++d) { vo[d] = validf[d] * v0; vi[d] = validf[d] * v0; }
    if (act) {
#pragma unroll
        for (int s = 0; s < 4; ++s) xpub[s][t] = make_float2(vo[s], vi[s]);
    }
    __syncthreads();

    float L = 1.f;
    for (int it = 0; it <= PITERS; ++it) {
        // u = A v per node: u_in = v_int - sum(incoming), u_out = sum(outgoing) - v_int
        float inc = vi[0] + vi[1] + vi[2] + vi[3];
        float outg = vo[0] + vo[1] + vo[2] + vo[3];
#pragma unroll
        for (int d = 4; d < 8; ++d) {
            const float2 r = xpub[7 - d][nbr[d]];  // (vo, vi) of neighbor slot 7-d
            inc += validf[d] * r.x;                // neighbor's E_out toward us
            outg += validf[d] * r.y;               // neighbor's E_in = our outgoing
        }
        const float u_in = v_int - inc;
        const float u_out = outg - v_int;

        if (it == PITERS) {
            const float p = act ? (u_in * u_in + u_out * u_out) : 0.f;
            L = sqrtf(block_reduce_sum(p, red, scal));
            break;
        }

        if (act) ypub[t] = make_float2(u_in, u_out);
        __syncthreads();

        // w = A^T u per edge: w = u[tail] - u[head]
        const float w_int = u_in - u_out;
        float wo[4], wi[4];
        float p = act ? (w_int * w_int) : 0.f;
#pragma unroll
        for (int d = 0; d < 4; ++d) {
            const float2 r = ypub[nbr[d]];             // (u_in, u_out) of neighbor
            const float a = validf[d] * (u_out - r.x); // E_out: tail u_out(t), head u_in(nbr)
            const float b = validf[d] * (r.y - u_in);  // E_in : tail u_out(nbr), head u_in(t)
            wo[d] = a;
            wi[d] = b;
            p += a * a + b * b;
        }
        const float rn = 1.f / sqrtf(block_reduce_sum(p, red, scal));
        v_int = w_int * rn;
#pragma unroll
        for (int s = 0; s < 4; ++s) { vo[s] = wo[s] * rn; vi[s] = wi[s] * rn; }
        if (act) {
#pragma unroll
            for (int s = 0; s < 4; ++s) xpub[s][t] = make_float2(vo[s], vi[s]);
        }
        __syncthreads();
    }

    const float tau = 0.95f / L;
    const float sigma = tau;
    float tv[4];
#pragma unroll
    for (int d = 0; d < 4; ++d) tv[d] = validf[d] * tau;  // invalid edges: step 0 -> stay 0

    // ---------------- PDHG main loop ----------------
    float x_int = 0.f, y_in = 0.f, y_out = 0.f;
    float xo[4] = {0.f, 0.f, 0.f, 0.f}, xi[4] = {0.f, 0.f, 0.f, 0.f};
    const float sb_in = (t == 0) ? sigma : 0.f;            // sigma * b[source]
    const float sb_out = (t == CELLS - 1) ? -sigma : 0.f;  // sigma * b[sink] (b = -1)

    if (act) ypub[t] = make_float2(0.f, 0.f);
    __syncthreads();

    for (int it = 0; it < NITERS; ++it) {
        float xb_int, xbo[4], xbi[4];
        if (act) {
            // ---- phase A: x update over owned edges ----
            const float g = c_int + (y_in - y_out);
            const float xn = fminf(fmaxf(fmaf(-tau, g, x_int), 0.f), 1.f);
            xb_int = 2.f * xn - x_int;
            x_int = xn;
#pragma unroll
            for (int d = 0; d < 4; ++d) {
                const float2 yn2 = ypub[nbr[d]];  // (y_in, y_out) of neighbor
                const float go = y_out - yn2.x;   // E_out grad
                const float xno = fminf(fmaxf(fmaf(-tv[d], go, xo[d]), 0.f), 1.f);
                xbo[d] = 2.f * xno - xo[d];
                xo[d] = xno;
                const float gi = yn2.y - y_in;    // E_in grad
                const float xni = fminf(fmaxf(fmaf(-tv[d], gi, xi[d]), 0.f), 1.f);
                xbi[d] = 2.f * xni - xi[d];
                xi[d] = xni;
                xpub[d][t] = make_float2(xbo[d], xbi[d]);
            }
        }
        __syncthreads();
        if (act) {
            // ---- phase B: y update per node ----
            float inc = xbi[0] + xbi[1] + xbi[2] + xbi[3];
            float outg = xbo[0] + xbo[1] + xbo[2] + xbo[3];
#pragma unroll
            for (int d = 4; d < 8; ++d) {
                const float2 r = xpub[7 - d][nbr[d]];  // neighbor slot: (xb_out, xb_in)
                inc += r.x;   // their E_out -> incoming to us
                outg += r.y;  // their E_in  -> outgoing from us
            }
            y_in += sigma * (xb_int - inc) - sb_in;
            y_out += sigma * (outg - xb_int) - sb_out;
            ypub[t] = make_float2(y_in, y_out);
        }
        __syncthreads();
    }

    if (act) out[t] = x_int;
}

extern "C" void kernel_launch(void* const* d_in, const int* in_sizes, int n_in,
                              void* d_out, int out_size, void* d_ws, size_t ws_size,
                              hipStream_t stream) {
    const float* weights = (const float*)d_in[0];  // (30,30) f32
    // d_in[1] (dense A) and d_in[2] (b) unused: incidence rebuilt from index math;
    // algorithm is equivariant under edge relabeling (v0 constant, x0=y0=0).
    float* out = (float*)d_out;  // 900 f32
    (void)in_sizes; (void)n_in; (void)out_size; (void)d_ws; (void)ws_size;

    hipLaunchKernelGGL(pdhg_grid_lp, dim3(1), dim3(NT), 0, stream, weights, out);
}